// Round 4
// baseline (171.570 us; speedup 1.0000x reference)
//
#include <hip/hip_runtime.h>
#include <hip/hip_bf16.h>
#include <math.h>

#define NH 8
#define HS 64
#define VOCAB 16384
#define QPH 2048                         // queries per head = b(4) * t(512)
#define NSLICE 32                        // vocab slices (512 rows each)
// fold 1/sqrt(512) * log2(e) into Q so the epilogue is p = exp2(score)
#define QSCALE (0.04419417382415922f * 1.4426950408889634f)

typedef __attribute__((ext_vector_type(8))) short bf16x8;
typedef __attribute__((ext_vector_type(4))) float f32x4;

static __device__ __forceinline__ unsigned short f2bf(float f) {
    __hip_bfloat16 h = __float2bfloat16(f);
    unsigned short u;
    __builtin_memcpy(&u, &h, 2);
    return u;
}

static __device__ __forceinline__ float fexp2(float x) {
#if __has_builtin(__builtin_amdgcn_exp2f)
    return __builtin_amdgcn_exp2f(x);     // v_exp_f32 directly
#else
    return __expf(x * 0.6931471805599453f);
#endif
}

// async global->LDS. HW semantics (m104): LDS dest = WAVE-UNIFORM base + lane*16.
// Dest must be passed wave-uniform (R12 passed tid-divergent pointers -> container
// fault). Src stays per-lane.
static __device__ __forceinline__ void stage16(const void* g, void* l) {
    __builtin_amdgcn_global_load_lds(
        (const __attribute__((address_space(1))) void*)g,
        (__attribute__((address_space(3))) void*)l, 16, 0, 0);
}

// ---------------- Kernel 1a: eprep — E -> bf16 (FRAG-ORDERED, GATHER) + g -----------
// Gather form — thread OWNS output chunk (linear coalesced ushort4 write), reads the
// permuted input f32x4 (32B segments, L2-absorbed). Layout:
//   ushort4 chunk o4 = (n*1024+T)*256 + h*128 + q*32 + r*2 + jh
//   holds E[v=T*16+r][c = h*32 + q*8 + jh*4 .. +3] as 4 bf16.
// One 2048B tile T = [kf h][quad q][row r][jh] — byte kf*1024+q*256+r*16+jh*8, i.e.
// exactly lane(q,r)'s 16B A-frag at (lane*16 + kf*1024).
// g[n][v] = E[n][v,:].dec_w via per-block LDS reduction (block == one (n,T) tile).
__global__ void eprep(const float* __restrict__ emb, const float* __restrict__ dec_w,
                      unsigned short* __restrict__ ebf, float* __restrict__ g) {
    __shared__ float red[256];
    int tid = threadIdx.x;
    int nt  = blockIdx.x;                 // n*1024 + T  (grid 8192)
    int h   = (tid >> 7) & 1;
    int q   = (tid >> 5) & 3;
    int r   = (tid >> 1) & 15;
    int jh  = tid & 1;
    int n   = nt >> 10;
    int T   = nt & 1023;
    int row = n * VOCAB + T * 16 + r;
    int c4  = h * 8 + q * 2 + jh;         // f32x4 column index
    f32x4 vv = ((const f32x4*)emb)[(size_t)row * 16 + c4];
    ushort4 u = make_ushort4(f2bf(vv.x), f2bf(vv.y), f2bf(vv.z), f2bf(vv.w));
    ((ushort4*)ebf)[(size_t)nt * 256 + tid] = u;   // linear, coalesced
    const float* dw = dec_w + n * 64 + c4 * 4;
    float p = vv.x * dw[0] + vv.y * dw[1] + vv.z * dw[2] + vv.w * dw[3];
    red[tid] = p;
    __syncthreads();
    if (tid < 16) {                       // thread tid sums row r=tid over 16 c4 slots
        float s = 0.f;
        #pragma unroll
        for (int m = 0; m < 16; ++m)
            s += red[((m >> 3) * 128) + (((m & 7) >> 1) * 32) + tid * 2 + (m & 1)];
        g[n * VOCAB + T * 16 + tid] = s;
    }
}

// ---------------- Kernel 1b: qprep — LayerNorm(enc(x)+PE)*QSCALE -> bf16 (FRAG-ORD) -
// Output frag-ordered per 128-q group so attn can global_load_lds Q linearly and
// ds_read_b128 at (lane*16 + immediate):
//   short idx = (head*16 + q>>7)*8192 + ((qt*2+kf)*4 + quad)*128 + l15*8 + j
//   where qt=(q>>4)&7, l15=q&15, kf=h>>5, quad=(h>>3)&3, j=h&7.
__global__ void qprep(const float* __restrict__ x, const float* __restrict__ enc_w,
                      const float* __restrict__ enc_b, const float* __restrict__ ln_w,
                      const float* __restrict__ ln_b, unsigned short* __restrict__ qbf) {
    int row  = blockIdx.x * 4 + (threadIdx.x >> 6);  // n*2048 + q
    int h    = threadIdx.x & 63;
    int n = row >> 11;
    int q = row & 2047;
    int t = q & 511;
    float xv = x[q];
    int d = n * 64 + h;
    float h2  = (float)(h & ~1);
    float div = __expf(h2 * (-9.210340371976184f / 64.0f));
    float ang = (float)t * div;
    float pe  = (h & 1) ? __cosf(ang) : __sinf(ang);
    float v = xv * enc_w[d] + enc_b[d] + pe;
    float s = v;
    #pragma unroll
    for (int off = 1; off < 64; off <<= 1) s += __shfl_xor(s, off);
    float mu = s * (1.0f / 64.0f);
    float dd = v - mu;
    float s2 = dd * dd;
    #pragma unroll
    for (int off = 1; off < 64; off <<= 1) s2 += __shfl_xor(s2, off);
    float var = s2 * (1.0f / 64.0f);
    float y = dd * rsqrtf(var + 1e-5f) * ln_w[h] + ln_b[h];
    int qt   = (q >> 4) & 7;
    int l15  = q & 15;
    int kf   = h >> 5;
    int quad = (h >> 3) & 3;
    int j    = h & 7;
    size_t idx = ((size_t)(n * 16 + (q >> 7)) * 8192)
               + ((size_t)((qt * 2 + kf) * 4 + quad) * 128) + l15 * 8 + j;
    qbf[idx] = f2bf(y * QSCALE);
}

// ---------------- Kernel 2: attn (R14 — R13 + E prefetch pipeline) -------------------
// grid 1024 = vgroup(8)*128 + qgroup(16)*8 + head(8); block 256 (4 waves).
// blockIdx % 8 == head: XCD-pinned — head's ebf (2MB) + qbf (256KB) + g (64KB) L2-fit.
// Block covers 128 q x 2048 v: Q (16KB, frag-ordered) SHARED in LDS by all 4 waves;
// wave w owns v-slice vgroup*4+w (512 v, 8 iters x 64 v).
// R14 vs R13 (52.3us, VALUBusy 53%, dur >> busiest-pipe busy => latency-exposed):
//  - R13's clobber fenced the E loads too: each iter's 8 L2 loads (~300cy) issued
//    only after the previous epilogue — exposed at every iteration head.
//  - NOW: next iter's E loads (an[]) issue BEFORE the clobber, i.e. at the TOP of the
//    current iter's 1536-cycle compute region. They stay in flight across the clobber
//    (compiler emits counted vmcnt, T4-style), latency fully hidden. Wrap (it+1)&7
//    avoids the tail branch (8 wasted L2-hit loads per wave, negligible).
//  - Q still LDS-resident, re-read per use after the clobber (R13's anti-spill
//    discipline, proven: WRITE_SIZE=4096 exactly). TRIPWIRE: WRITE >> 4MB = an[]
//    pushed regalloc into spilling; VGPR should land ~90-110.
__global__ void __launch_bounds__(256, 4)
attn(const unsigned short* __restrict__ qbf, const unsigned short* __restrict__ ebf,
     const float* __restrict__ g, float2* __restrict__ part) {
    __shared__ __attribute__((aligned(16))) char smem[16384 + 8192];
    float* gl = (float*)(smem + 16384);

    int tid  = threadIdx.x;
    int w    = tid >> 6;
    int lane = tid & 63;
    int quad = lane >> 4;
    int l15  = lane & 15;
    int head   = blockIdx.x & 7;
    int qgroup = (blockIdx.x >> 3) & 15;   // 16 groups x 128 q
    int vgroup = blockIdx.x >> 7;          // 8 groups x 2048 v
    int vslice = vgroup * 4 + w;           // global 512-v slice id (0..31)

    const char*  qsrc = (const char*)qbf + (size_t)(head * 16 + qgroup) * 16384;
    const char*  esrc = (const char*)ebf + (size_t)head * 2097152 + (size_t)vslice * 65536;
    const float* gp   = g + head * VOCAB + vgroup * 2048;

    // prologue: stage Q (16KB) + g (8KB); dest WAVE-UNIFORM (+w*1024), HW adds
    // lane*16 -> lane l of wave w lands at byte tid*16. Also issue it=0 E loads —
    // they drain under the same vmcnt(0) at the barrier.
    #pragma unroll
    for (int k = 0; k < 4; ++k)
        stage16(qsrc + k * 4096 + tid * 16, smem + k * 4096 + w * 1024);
    stage16((const char*)gp + tid * 16,        (char*)gl + w * 1024);
    stage16((const char*)gp + 4096 + tid * 16, (char*)gl + 4096 + w * 1024);

    bf16x8 a[4][2];
    #pragma unroll
    for (int vt = 0; vt < 4; ++vt) {
        a[vt][0] = *(const bf16x8*)(esrc + vt * 2048 +        lane * 16);
        a[vt][1] = *(const bf16x8*)(esrc + vt * 2048 + 1024 + lane * 16);
    }

    float num[8] = {0.f, 0.f, 0.f, 0.f, 0.f, 0.f, 0.f, 0.f};
    float den[8] = {0.f, 0.f, 0.f, 0.f, 0.f, 0.f, 0.f, 0.f};
    const f32x4 z = {0.f, 0.f, 0.f, 0.f};
    const float* gw = gl + w * 512;

    __syncthreads();   // s_waitcnt vmcnt(0) lgkmcnt(0) + s_barrier

    #pragma clang loop unroll(disable)
    for (int it = 0; it < 8; ++it) {
        // prefetch next iter's E A-frags BEFORE the clobber: issued at the top of
        // this iter's compute, in flight across it (counted vmcnt, never drained).
        bf16x8 an[4][2];
        const char* eb = esrc + ((it + 1) & 7) * 8192;
        #pragma unroll
        for (int vt = 0; vt < 4; ++vt) {
            an[vt][0] = *(const bf16x8*)(eb + vt * 2048 +        lane * 16);
            an[vt][1] = *(const bf16x8*)(eb + vt * 2048 + 1024 + lane * 16);
        }
        // block LICM on the Q ds_reads (would spill, R11 failure mode). Loads above
        // stay above (asm memory clobber orders memory ops both ways); values in
        // VGPRs flow through freely.
        asm volatile("" ::: "memory");

        f32x4 gv[4];
        #pragma unroll
        for (int vt = 0; vt < 4; ++vt)
            gv[vt] = *(const f32x4*)(gw + it * 64 + vt * 16 + quad * 4);

        #pragma unroll
        for (int qt = 0; qt < 8; ++qt) {
            const char* qb = smem + qt * 2048 + lane * 16;
            bf16x8 q0 = *(const bf16x8*)(qb);
            bf16x8 q1 = *(const bf16x8*)(qb + 1024);
            #pragma unroll
            for (int vt = 0; vt < 4; ++vt) {
                f32x4 acc = __builtin_amdgcn_mfma_f32_16x16x32_bf16(a[vt][0], q0, z, 0, 0, 0);
                acc       = __builtin_amdgcn_mfma_f32_16x16x32_bf16(a[vt][1], q1, acc, 0, 0, 0);
                // D layout: col=l15=q, row=quad*4+r = v-within-16-tile
                #pragma unroll
                for (int r = 0; r < 4; ++r) {
                    float p = fexp2(acc[r]);
                    den[qt] += p;
                    num[qt] += p * gv[vt][r];
                }
            }
        }
        // rotate prefetch -> current (register renames / movs, ~64cyc, 3% of iter)
        #pragma unroll
        for (int vt = 0; vt < 4; ++vt) {
            a[vt][0] = an[vt][0];
            a[vt][1] = an[vt][1];
        }
    }

    // reduce across quads (same l15 = same q)
    #pragma unroll
    for (int qt = 0; qt < 8; ++qt) {
        num[qt] += __shfl_xor(num[qt], 16); num[qt] += __shfl_xor(num[qt], 32);
        den[qt] += __shfl_xor(den[qt], 16); den[qt] += __shfl_xor(den[qt], 32);
    }
    // slotted partials (no atomics): part[vslice][head][q]; quad commits 2 q-tiles
    #pragma unroll
    for (int j = 0; j < 2; ++j) {
        int qt = quad * 2 + j;
        int qg = qgroup * 128 + qt * 16 + l15;
        part[((size_t)vslice * NH + head) * QPH + qg] = make_float2(num[qt], den[qt]);
    }
}

// ---------------- Kernel 3: fin — parallel over (n,q), LDS reduce over n -------------
__global__ void fin(const float2* __restrict__ part, const float* __restrict__ dec_b,
                    float* __restrict__ out) {
    __shared__ float red[8][32];
    int t  = threadIdx.x;
    int ql = t & 31;
    int n  = t >> 5;
    int q  = blockIdx.x * 32 + ql;
    float nv = 0.f, dv = 0.f;
    #pragma unroll            // full unroll: 32 outstanding 8B loads (was 8)
    for (int sl = 0; sl < NSLICE; ++sl) {
        float2 nd = part[((size_t)sl * NH + n) * QPH + q];
        nv += nd.x; dv += nd.y;
    }
    red[n][ql] = nv / dv;
    __syncthreads();
    if (t < 32) {
        float s = dec_b[0];
        #pragma unroll
        for (int m = 0; m < NH; ++m) s += red[m][t];
        out[q] = s;
    }
}

extern "C" void kernel_launch(void* const* d_in, const int* in_sizes, int n_in,
                              void* d_out, int out_size, void* d_ws, size_t ws_size,
                              hipStream_t stream) {
    const float* x     = (const float*)d_in[0];
    const float* emb   = (const float*)d_in[1];
    const float* enc_w = (const float*)d_in[2];
    const float* enc_b = (const float*)d_in[3];
    const float* ln_w  = (const float*)d_in[4];
    const float* ln_b  = (const float*)d_in[5];
    const float* dec_w = (const float*)d_in[6];
    const float* dec_b = (const float*)d_in[7];
    float* out = (float*)d_out;

    char* ws = (char*)d_ws;
    unsigned short* qbf  = (unsigned short*)(ws);                        // 2 MB
    unsigned short* ebf  = (unsigned short*)(ws + 2097152);              // 16 MB
    float*          g    = (float*)(ws + 2097152 + 16777216);            // 512 KB
    float2*         part = (float2*)(ws + 2097152 + 16777216 + 524288);  // 4 MB

    hipLaunchKernelGGL(eprep, dim3(8192), dim3(256), 0, stream, emb, dec_w, ebf, g);
    hipLaunchKernelGGL(qprep, dim3(4096), dim3(256), 0, stream, x, enc_w, enc_b, ln_w, ln_b, qbf);
    hipLaunchKernelGGL(attn,  dim3(1024), dim3(256), 0, stream, qbf, ebf, g, part);
    hipLaunchKernelGGL(fin,   dim3(64),   dim3(256), 0, stream, part, dec_b, out);
}

// Round 5
// 157.544 us; speedup vs baseline: 1.0890x; 1.0890x over previous
//
#include <hip/hip_runtime.h>
#include <hip/hip_bf16.h>
#include <math.h>

#define NH 8
#define HS 64
#define VOCAB 16384
#define QPH 2048                         // queries per head = b(4) * t(512)
#define NSLICE 32                        // vocab slices (512 rows each)
// fold 1/sqrt(512) * log2(e) into Q so the epilogue is p = exp2(score)
#define QSCALE (0.04419417382415922f * 1.4426950408889634f)

typedef __attribute__((ext_vector_type(8))) short bf16x8;
typedef __attribute__((ext_vector_type(4))) float f32x4;

static __device__ __forceinline__ unsigned short f2bf(float f) {
    __hip_bfloat16 h = __float2bfloat16(f);
    unsigned short u;
    __builtin_memcpy(&u, &h, 2);
    return u;
}

static __device__ __forceinline__ float fexp2(float x) {
#if __has_builtin(__builtin_amdgcn_exp2f)
    return __builtin_amdgcn_exp2f(x);     // v_exp_f32 directly
#else
    return __expf(x * 0.6931471805599453f);
#endif
}

// async global->LDS. HW: LDS dest = WAVE-UNIFORM base + lane*16 (R12 fault lesson).
static __device__ __forceinline__ void stage16(const void* g, void* l) {
    __builtin_amdgcn_global_load_lds(
        (const __attribute__((address_space(1))) void*)g,
        (__attribute__((address_space(3))) void*)l, 16, 0, 0);
}

// ---------------- Kernel 1a: eprep — R15: coalesced read + LDS permute --------------
// R13's eprep read emb PERMUTED at 16B granularity (1KB strides) -> ~4x HBM over-fetch
// on a cold 64MB input (~40us, the hidden majority of non-attn time). Now: LINEAR
// coalesced f32x4 read (thread tid reads tile chunk tid), permute through LDS, LINEAR
// coalesced ushort4 write. Frag layout of ebf unchanged (verified R13-passing):
//   within tile (n,T): chunk h*128 + q*32 + r*2 + jh  holds E[v=T*16+r][c4=h*8+q*2+jh]
// g[n][v] = E[n][v,:].dec_w via 16-lane shfl (lanes of a row are contiguous now).
__global__ void eprep(const float* __restrict__ emb, const float* __restrict__ dec_w,
                      unsigned short* __restrict__ ebf, float* __restrict__ g) {
    __shared__ ushort4 lu[256];
    __shared__ float red[16];
    int tid = threadIdx.x;
    int nt  = blockIdx.x;                 // n*1024 + T  (grid 8192)
    int n   = nt >> 10;
    int r   = tid >> 4;                   // row within 16-row tile
    int c4  = tid & 15;                   // f32x4 column
    f32x4 vv = ((const f32x4*)emb)[(size_t)nt * 256 + tid];   // LINEAR read
    ushort4 u = make_ushort4(f2bf(vv.x), f2bf(vv.y), f2bf(vv.z), f2bf(vv.w));
    int h = c4 >> 3, q = (c4 >> 1) & 3, jh = c4 & 1;
    lu[h * 128 + q * 32 + r * 2 + jh] = u;                    // permute via LDS
    const float* dw = dec_w + n * 64 + c4 * 4;
    float p = vv.x * dw[0] + vv.y * dw[1] + vv.z * dw[2] + vv.w * dw[3];
    p += __shfl_xor(p, 1); p += __shfl_xor(p, 2);
    p += __shfl_xor(p, 4); p += __shfl_xor(p, 8);             // 16-lane row group
    if (c4 == 0) red[r] = p;
    __syncthreads();
    ((ushort4*)ebf)[(size_t)nt * 256 + tid] = lu[tid];        // LINEAR write
    if (tid < 16) g[n * VOCAB + (nt & 1023) * 16 + tid] = red[tid];
}

// ---------------- Kernel 1b: qprep — R15: one wave per t, pe computed ONCE ----------
// R13 paid sincos+exp per (n,b,t,h) element — 32x redundant (pe depends only on t,h),
// ~15us of trans-pipe. Now: wave = one t (lanes = h), pe/div computed once, loop over
// the 32 (n,b) rows reusing it. Output layout (64-q granule for R15 attn):
//   short idx = (n*32 + q>>6)*4096 + ((qt*2+kf)*4 + quad)*128 + l15*8 + j
//   qt=(q>>4)&3, l15=q&15, kf=h>>5, quad=(h>>3)&3, j=h&7.
__global__ void qprep(const float* __restrict__ x, const float* __restrict__ enc_w,
                      const float* __restrict__ enc_b, const float* __restrict__ ln_w,
                      const float* __restrict__ ln_b, unsigned short* __restrict__ qbf) {
    int w = threadIdx.x >> 6;
    int h = threadIdx.x & 63;
    int t = blockIdx.x * 4 + w;           // grid 128 -> t in [0,512)
    float h2  = (float)(h & ~1);
    float div = __expf(h2 * (-9.210340371976184f / 64.0f));
    float ang = (float)t * div;
    float pe  = (h & 1) ? __cosf(ang) : __sinf(ang);
    float lw = ln_w[h], lb = ln_b[h];
    int kf = h >> 5, quad = (h >> 3) & 3, j = h & 7;
    int fragoff = ((kf * 4 + quad) * 128) + j;   // + qt*1024 + l15*8 added per row
    #pragma unroll
    for (int n = 0; n < NH; ++n) {
        float ew = enc_w[n * 64 + h];
        float eb = enc_b[n * 64 + h];
        #pragma unroll
        for (int b = 0; b < 4; ++b) {
            int q = b * 512 + t;
            float v = x[q] * ew + eb + pe;
            float s = v;
            #pragma unroll
            for (int off = 1; off < 64; off <<= 1) s += __shfl_xor(s, off);
            float mu = s * (1.0f / 64.0f);
            float dd = v - mu;
            float s2 = dd * dd;
            #pragma unroll
            for (int off = 1; off < 64; off <<= 1) s2 += __shfl_xor(s2, off);
            float var = s2 * (1.0f / 64.0f);
            float y = dd * rsqrtf(var + 1e-5f) * lw + lb;
            int qt = (q >> 4) & 3, l15 = q & 15;
            size_t idx = ((size_t)(n * 32 + (q >> 6)) * 4096)
                       + qt * 1024 + l15 * 8 + fragoff;
            qbf[idx] = f2bf(y * QSCALE);
        }
    }
}

// ---------------- Kernel 2: attn (R15 — 64-reg-native shape, 8 waves/SIMD) ----------
// grid 2048 = vgroup(8)*256 + qgroup(32)*8 + head(8); block 256 (4 waves).
// blockIdx % 8 == head: XCD-pinned (head's ebf 2MB + qbf 256KB + g 64KB L2-fit).
// Block = 64 q x 2048 v; Q (8KB) + g (8KB) in LDS; wave w owns vslice vgroup*4+w
// (512 v, 8 iters x 64 v). part layout unchanged (32 slices).
// R15 vs R13 (52.3us, VALUBusy 53%, 4 waves/SIMD, compiler re-juggling E at 64 regs):
//  - THE BACKEND ALLOCATES 64 VGPRS FOR THIS KERNEL NO MATTER WHAT (R13 ok, R14
//    spilled 190MB trying to exceed it). So: vt-OUTER / qt-INNER -> live set ~50 regs
//    (one a-pair + gv + num/den[4] + transient q-frags). No manual prefetch (R14).
//  - Latency hiding comes from occupancy instead: q split 32-ways halves LDS+VALU per
//    block; launch_bounds(256,8) + grid 2048 = 8 blocks/CU, 8 waves/SIMD, one tranche.
//  - Clobber inside vt loop: Q ds_reads stay transient (anti-LICM, R11 lesson).
//  - TRIPWIRE: WRITE_SIZE must stay 4096KB exactly; VGPR=64.
__global__ void __launch_bounds__(256, 8)
attn(const unsigned short* __restrict__ qbf, const unsigned short* __restrict__ ebf,
     const float* __restrict__ g, float2* __restrict__ part) {
    __shared__ __attribute__((aligned(16))) char smem[8192 + 8192];
    float* gl = (float*)(smem + 8192);

    int tid  = threadIdx.x;
    int w    = tid >> 6;
    int lane = tid & 63;
    int quad = lane >> 4;
    int l15  = lane & 15;
    int head   = blockIdx.x & 7;
    int qgroup = (blockIdx.x >> 3) & 31;   // 32 groups x 64 q
    int vgroup = blockIdx.x >> 8;          // 8 groups x 2048 v
    int vslice = vgroup * 4 + w;           // global 512-v slice id (0..31)

    const char*  qsrc = (const char*)qbf + (size_t)(head * 32 + qgroup) * 8192;
    const char*  esrc = (const char*)ebf + (size_t)head * 2097152 + (size_t)vslice * 65536;
    const float* gp   = g + head * VOCAB + vgroup * 2048;

    // prologue: stage Q (8KB) + g (8KB); dest WAVE-UNIFORM (+w*1024), HW adds lane*16.
    stage16(qsrc + tid * 16,        smem + w * 1024);
    stage16(qsrc + 4096 + tid * 16, smem + 4096 + w * 1024);
    stage16((const char*)gp + tid * 16,        (char*)gl + w * 1024);
    stage16((const char*)gp + 4096 + tid * 16, (char*)gl + 4096 + w * 1024);
    __syncthreads();   // vmcnt(0) drain + barrier (once)

    float num[4] = {0.f, 0.f, 0.f, 0.f};
    float den[4] = {0.f, 0.f, 0.f, 0.f};
    const f32x4 z = {0.f, 0.f, 0.f, 0.f};
    const float* gw = gl + w * 512;

    #pragma clang loop unroll(disable)
    for (int it = 0; it < 8; ++it) {
        const char* eb = esrc + it * 8192;
        #pragma unroll
        for (int vt = 0; vt < 4; ++vt) {
            // clobber per vt: Q ds_reads below stay transient (no LICM -> no spill);
            // a-pair loads issue here, latency covered by 8-wave TLP.
            asm volatile("" ::: "memory");
            bf16x8 a0 = *(const bf16x8*)(eb + vt * 2048 +        lane * 16);
            bf16x8 a1 = *(const bf16x8*)(eb + vt * 2048 + 1024 + lane * 16);
            f32x4 gv  = *(const f32x4*)(gw + it * 64 + vt * 16 + quad * 4);
            #pragma unroll
            for (int qt = 0; qt < 4; ++qt) {
                const char* qb = smem + qt * 2048 + lane * 16;
                bf16x8 q0 = *(const bf16x8*)(qb);
                bf16x8 q1 = *(const bf16x8*)(qb + 1024);
                f32x4 acc = __builtin_amdgcn_mfma_f32_16x16x32_bf16(a0, q0, z, 0, 0, 0);
                acc       = __builtin_amdgcn_mfma_f32_16x16x32_bf16(a1, q1, acc, 0, 0, 0);
                // D layout: col=l15=q, row=quad*4+r = v-within-16-tile
                #pragma unroll
                for (int r = 0; r < 4; ++r) {
                    float p = fexp2(acc[r]);
                    den[qt] += p;
                    num[qt] += p * gv[r];
                }
            }
        }
    }

    // reduce across quads (same l15 = same q)
    #pragma unroll
    for (int qt = 0; qt < 4; ++qt) {
        num[qt] += __shfl_xor(num[qt], 16); num[qt] += __shfl_xor(num[qt], 32);
        den[qt] += __shfl_xor(den[qt], 16); den[qt] += __shfl_xor(den[qt], 32);
    }
    // slotted partials: quad commits its own q-tile (qt == quad)
    int qg = qgroup * 64 + quad * 16 + l15;
    part[((size_t)vslice * NH + head) * QPH + qg] = make_float2(num[quad], den[quad]);
}

// ---------------- Kernel 3: fin — parallel over (n,q), LDS reduce over n -------------
__global__ void fin(const float2* __restrict__ part, const float* __restrict__ dec_b,
                    float* __restrict__ out) {
    __shared__ float red[8][32];
    int t  = threadIdx.x;
    int ql = t & 31;
    int n  = t >> 5;
    int q  = blockIdx.x * 32 + ql;
    float nv = 0.f, dv = 0.f;
    #pragma unroll            // full unroll: 32 outstanding 8B loads
    for (int sl = 0; sl < NSLICE; ++sl) {
        float2 nd = part[((size_t)sl * NH + n) * QPH + q];
        nv += nd.x; dv += nd.y;
    }
    red[n][ql] = nv / dv;
    __syncthreads();
    if (t < 32) {
        float s = dec_b[0];
        #pragma unroll
        for (int m = 0; m < NH; ++m) s += red[m][t];
        out[q] = s;
    }
}

extern "C" void kernel_launch(void* const* d_in, const int* in_sizes, int n_in,
                              void* d_out, int out_size, void* d_ws, size_t ws_size,
                              hipStream_t stream) {
    const float* x     = (const float*)d_in[0];
    const float* emb   = (const float*)d_in[1];
    const float* enc_w = (const float*)d_in[2];
    const float* enc_b = (const float*)d_in[3];
    const float* ln_w  = (const float*)d_in[4];
    const float* ln_b  = (const float*)d_in[5];
    const float* dec_w = (const float*)d_in[6];
    const float* dec_b = (const float*)d_in[7];
    float* out = (float*)d_out;

    char* ws = (char*)d_ws;
    unsigned short* qbf  = (unsigned short*)(ws);                        // 2 MB
    unsigned short* ebf  = (unsigned short*)(ws + 2097152);              // 16 MB
    float*          g    = (float*)(ws + 2097152 + 16777216);            // 512 KB
    float2*         part = (float2*)(ws + 2097152 + 16777216 + 524288);  // 4 MB

    hipLaunchKernelGGL(eprep, dim3(8192), dim3(256), 0, stream, emb, dec_w, ebf, g);
    hipLaunchKernelGGL(qprep, dim3(128),  dim3(256), 0, stream, x, enc_w, enc_b, ln_w, ln_b, qbf);
    hipLaunchKernelGGL(attn,  dim3(2048), dim3(256), 0, stream, qbf, ebf, g, part);
    hipLaunchKernelGGL(fin,   dim3(64),   dim3(256), 0, stream, part, dec_b, out);
}

// Round 8
// 155.871 us; speedup vs baseline: 1.1007x; 1.0107x over previous
//
#include <hip/hip_runtime.h>
#include <hip/hip_bf16.h>
#include <math.h>

#define NH 8
#define HS 64
#define VOCAB 16384
#define QPH 2048                         // queries per head = b(4) * t(512)
#define NSLICE 32                        // vocab slices (512 rows each)
// fold 1/sqrt(512) * log2(e) into Q so the epilogue is p = exp2(score)
#define QSCALE (0.04419417382415922f * 1.4426950408889634f)

typedef __attribute__((ext_vector_type(8))) short bf16x8;
typedef __attribute__((ext_vector_type(4))) float f32x4;

static __device__ __forceinline__ unsigned short f2bf(float f) {
    __hip_bfloat16 h = __float2bfloat16(f);
    unsigned short u;
    __builtin_memcpy(&u, &h, 2);
    return u;
}

static __device__ __forceinline__ float fexp2(float x) {
#if __has_builtin(__builtin_amdgcn_exp2f)
    return __builtin_amdgcn_exp2f(x);     // v_exp_f32 directly
#else
    return __expf(x * 0.6931471805599453f);
#endif
}

// async global->LDS. HW semantics (hard-won over R12/R16/R17):
//  - LDS dest operand = WAVE-UNIFORM base; HW adds lane*16 (divergent dest -> fault).
//  - global SRC operand = PER-LANE address; caller MUST include lane*16 (R17 bug:
//    uniform src replicated 16 bytes across the whole 1KB range).
//  - one call moves exactly 1KB per wave (R16 bug: half-staged tiles).
static __device__ __forceinline__ void stage16(const void* g, void* l) {
    __builtin_amdgcn_global_load_lds(
        (const __attribute__((address_space(1))) void*)g,
        (__attribute__((address_space(3))) void*)l, 16, 0, 0);
}

// ---------------- Kernel 1a: eprep — coalesced read + LDS permute + g ---------------
// LINEAR coalesced f32x4 read, permute via LDS, LINEAR coalesced ushort4 write.
// ebf frag layout (R13-verified): within tile (n,T) [2048B]: byte kf*1024 + lane*16
// is lane(quad,r)'s A-frag half; chunk h*128+q*32+r*2+jh holds E[v=T*16+r][c4=h*8+q*2+jh].
// g[n][v] = E[n][v,:].dec_w via 16-lane shfl row groups.
__global__ void eprep(const float* __restrict__ emb, const float* __restrict__ dec_w,
                      unsigned short* __restrict__ ebf, float* __restrict__ g) {
    __shared__ ushort4 lu[256];
    __shared__ float red[16];
    int tid = threadIdx.x;
    int nt  = blockIdx.x;                 // n*1024 + T  (grid 8192)
    int n   = nt >> 10;
    int r   = tid >> 4;                   // row within 16-row tile
    int c4  = tid & 15;                   // f32x4 column
    f32x4 vv = ((const f32x4*)emb)[(size_t)nt * 256 + tid];   // LINEAR read
    ushort4 u = make_ushort4(f2bf(vv.x), f2bf(vv.y), f2bf(vv.z), f2bf(vv.w));
    int h = c4 >> 3, q = (c4 >> 1) & 3, jh = c4 & 1;
    lu[h * 128 + q * 32 + r * 2 + jh] = u;                    // permute via LDS
    const float* dw = dec_w + n * 64 + c4 * 4;
    float p = vv.x * dw[0] + vv.y * dw[1] + vv.z * dw[2] + vv.w * dw[3];
    p += __shfl_xor(p, 1); p += __shfl_xor(p, 2);
    p += __shfl_xor(p, 4); p += __shfl_xor(p, 8);             // 16-lane row group
    if (c4 == 0) red[r] = p;
    __syncthreads();
    ((ushort4*)ebf)[(size_t)nt * 256 + tid] = lu[tid];        // LINEAR write
    if (tid < 16) g[n * VOCAB + (nt & 1023) * 16 + tid] = red[tid];
}

// ---------------- Kernel 1b: qprep — one wave per t, pe computed ONCE ---------------
// Frag-ordered 64-q granules (R15-verified):
//   short idx = (n*32 + q>>6)*4096 + ((qt*2+kf)*4 + quad)*128 + l15*8 + j
//   qt=(q>>4)&3, l15=q&15, kf=h>>5, quad=(h>>3)&3, j=h&7.
__global__ void qprep(const float* __restrict__ x, const float* __restrict__ enc_w,
                      const float* __restrict__ enc_b, const float* __restrict__ ln_w,
                      const float* __restrict__ ln_b, unsigned short* __restrict__ qbf) {
    int w = threadIdx.x >> 6;
    int h = threadIdx.x & 63;
    int t = blockIdx.x * 4 + w;           // grid 128 -> t in [0,512)
    float h2  = (float)(h & ~1);
    float div = __expf(h2 * (-9.210340371976184f / 64.0f));
    float ang = (float)t * div;
    float pe  = (h & 1) ? __cosf(ang) : __sinf(ang);
    float lw = ln_w[h], lb = ln_b[h];
    int kf = h >> 5, quad = (h >> 3) & 3, j = h & 7;
    int fragoff = ((kf * 4 + quad) * 128) + j;   // + qt*1024 + l15*8 added per row
    #pragma unroll
    for (int n = 0; n < NH; ++n) {
        float ew = enc_w[n * 64 + h];
        float eb = enc_b[n * 64 + h];
        #pragma unroll
        for (int b = 0; b < 4; ++b) {
            int q = b * 512 + t;
            float v = x[q] * ew + eb + pe;
            float s = v;
            #pragma unroll
            for (int off = 1; off < 64; off <<= 1) s += __shfl_xor(s, off);
            float mu = s * (1.0f / 64.0f);
            float dd = v - mu;
            float s2 = dd * dd;
            #pragma unroll
            for (int off = 1; off < 64; off <<= 1) s2 += __shfl_xor(s2, off);
            float var = s2 * (1.0f / 64.0f);
            float y = dd * rsqrtf(var + 1e-5f) * lw + lb;
            int qt = (q >> 4) & 3, l15 = q & 15;
            size_t idx = ((size_t)(n * 32 + (q >> 6)) * 4096)
                       + qt * 1024 + l15 * 8 + fragoff;
            qbf[idx] = f2bf(y * QSCALE);
        }
    }
}

// ---------------- Kernel 2: attn (R18 — R17 + per-lane src on in-loop stage) --------
// grid 4096 = qgroup(16)*256 + vslice(32)*8 + head(8); block 256 (4 waves).
// blockIdx % 8 == head: XCD-pinned (head's ebf 2MB + qbf 256KB + g 64KB L2-fit).
// Block = 128q x 512v; waves SHARE v: per iter one 64v E tile (8KB) is DMA-staged
// into an LDS double-buffer ONE ITER AHEAD — zero VGPR cost (the backend pins this
// kernel at ~64 arch VGPRs; R13/R14/R15 proved reg-batched E is impossible).
// Wave w owns q-tiles {2w, 2w+1}; 16 blocks/CU over 4-resident staggers block
// phases so barrier waits overlap other blocks' compute.
// R18 FIX vs R17 (absmax 0.096): in-loop stage src was missing lane*16 — uniform
// src replicates one 16B chunk across the tile. Prologue was correct all along.
// Race-freedom: stage at iter j writes buf[(j+1)&1]; its readers (iter j-1) all
// passed the end-of-(j-1) barrier; the DMA drains under the end-of-j barrier's
// vmcnt(0); iter j+1 then reads it. One barrier per iter.
// TRIPWIRE: WRITE_SIZE must stay 4096KB exactly (else spill returned).
__global__ void __launch_bounds__(256, 4)
attn(const unsigned short* __restrict__ qbf, const unsigned short* __restrict__ ebf,
     const float* __restrict__ g, float2* __restrict__ part) {
    __shared__ __attribute__((aligned(16))) char smem[16384 + 16384 + 2048];
    char*  elds = smem;                      // [2][8192] E double-buffer
    char*  qlds = smem + 16384;              // 16KB: 128q frag-ordered (2 granules)
    float* glds = (float*)(smem + 32768);    // 512 floats

    int tid  = threadIdx.x;
    int w    = tid >> 6;
    int lane = tid & 63;
    int quad = lane >> 4;
    int l15  = lane & 15;
    int head   = blockIdx.x & 7;
    int vslice = (blockIdx.x >> 3) & 31;   // 32 slices x 512 v
    int qgroup = blockIdx.x >> 8;          // 16 groups x 128 q

    const char* qsrc = (const char*)qbf + (size_t)(head * 32 + qgroup * 2) * 8192;
    const char* esrc = (const char*)ebf + (size_t)head * 2097152 + (size_t)vslice * 65536;
    const char* gsrc = (const char*)(g + head * VOCAB + vslice * 512);

    // prologue: stage Q (16KB = 4 calls x 4 waves), g (2KB), E tile 0 (8KB = 2 calls
    // x 4 waves). Dest wave-uniform (HW adds lane*16); src per-lane (+lane*16).
    #pragma unroll
    for (int k = 0; k < 4; ++k)
        stage16(qsrc + k * 4096 + w * 1024 + lane * 16, qlds + k * 4096 + w * 1024);
    if (w < 2)
        stage16(gsrc + w * 1024 + lane * 16, (char*)glds + w * 1024);
    stage16(esrc + w * 2048 +        lane * 16, elds + w * 2048);
    stage16(esrc + w * 2048 + 1024 + lane * 16, elds + w * 2048 + 1024);
    __syncthreads();   // vmcnt(0) drain + barrier

    float num0 = 0.f, num1 = 0.f, den0 = 0.f, den1 = 0.f;
    const f32x4 z = {0.f, 0.f, 0.f, 0.f};
    // wave w's two q-tile bases (block-local qt = 2w, 2w+1)
    const char* qb0 = qlds + (w >> 1) * 8192 + ((2 * w)     & 3) * 2048 + lane * 16;
    const char* qb1 = qlds + (w >> 1) * 8192 + ((2 * w + 1) & 3) * 2048 + lane * 16;

    #pragma clang loop unroll(disable)
    for (int it = 0; it < 8; ++it) {
        // async-stage next E tile — FULL 8KB, src PER-LANE (+lane*16). Wraps at 8;
        // it=7's extra stage into buf0 is harmless (buf1 is being read).
        {
            const char* ns = esrc + ((it + 1) & 7) * 8192 + w * 2048 + lane * 16;
            char*       nd = elds + ((it + 1) & 1) * 8192 + w * 2048;
            stage16(ns,        nd);
            stage16(ns + 1024, nd + 1024);
        }

        const char* eb = elds + (it & 1) * 8192;
        // q-frags hoisted per iter (4 ds_read_b128, 32 regs): B[k][n=q],
        // lane n=l15, k=quad*8+j (+kf*32 via the two halves)
        bf16x8 q00 = *(const bf16x8*)(qb0);
        bf16x8 q01 = *(const bf16x8*)(qb0 + 1024);
        bf16x8 q10 = *(const bf16x8*)(qb1);
        bf16x8 q11 = *(const bf16x8*)(qb1 + 1024);
        #pragma unroll
        for (int vt = 0; vt < 4; ++vt) {
            bf16x8 a0 = *(const bf16x8*)(eb + vt * 2048 +        lane * 16);
            bf16x8 a1 = *(const bf16x8*)(eb + vt * 2048 + 1024 + lane * 16);
            f32x4 gv  = *(const f32x4*)(glds + it * 64 + vt * 16 + quad * 4);
            f32x4 acc0 = __builtin_amdgcn_mfma_f32_16x16x32_bf16(a0, q00, z, 0, 0, 0);
            acc0       = __builtin_amdgcn_mfma_f32_16x16x32_bf16(a1, q01, acc0, 0, 0, 0);
            f32x4 acc1 = __builtin_amdgcn_mfma_f32_16x16x32_bf16(a0, q10, z, 0, 0, 0);
            acc1       = __builtin_amdgcn_mfma_f32_16x16x32_bf16(a1, q11, acc1, 0, 0, 0);
            // D layout: col=l15=q, row=quad*4+r = v-within-16-tile
            #pragma unroll
            for (int r = 0; r < 4; ++r) {
                float p0 = fexp2(acc0[r]);
                float p1 = fexp2(acc1[r]);
                den0 += p0; num0 += p0 * gv[r];
                den1 += p1; num1 += p1 * gv[r];
            }
        }
        __syncthreads();   // all waves done reading buf[it&1]; next DMA drained
    }

    // reduce across quads (same l15 = same q)
    num0 += __shfl_xor(num0, 16); num0 += __shfl_xor(num0, 32);
    den0 += __shfl_xor(den0, 16); den0 += __shfl_xor(den0, 32);
    num1 += __shfl_xor(num1, 16); num1 += __shfl_xor(num1, 32);
    den1 += __shfl_xor(den1, 16); den1 += __shfl_xor(den1, 32);
    // slotted partials: quad 0 commits qt=2w, quad 1 commits qt=2w+1
    if (quad < 2) {
        float nv = quad ? num1 : num0;     // cndmask, no runtime array index
        float dv = quad ? den1 : den0;
        int qg = qgroup * 128 + (w * 2 + quad) * 16 + l15;
        part[((size_t)vslice * NH + head) * QPH + qg] = make_float2(nv, dv);
    }
}

// ---------------- Kernel 3: fin — parallel over (n,q), LDS reduce over n -------------
__global__ void fin(const float2* __restrict__ part, const float* __restrict__ dec_b,
                    float* __restrict__ out) {
    __shared__ float red[8][32];
    int t  = threadIdx.x;
    int ql = t & 31;
    int n  = t >> 5;
    int q  = blockIdx.x * 32 + ql;
    float nv = 0.f, dv = 0.f;
    #pragma unroll            // full unroll: 32 outstanding 8B loads
    for (int sl = 0; sl < NSLICE; ++sl) {
        float2 nd = part[((size_t)sl * NH + n) * QPH + q];
        nv += nd.x; dv += nd.y;
    }
    red[n][ql] = nv / dv;
    __syncthreads();
    if (t < 32) {
        float s = dec_b[0];
        #pragma unroll
        for (int m = 0; m < NH; ++m) s += red[m][t];
        out[q] = s;
    }
}

extern "C" void kernel_launch(void* const* d_in, const int* in_sizes, int n_in,
                              void* d_out, int out_size, void* d_ws, size_t ws_size,
                              hipStream_t stream) {
    const float* x     = (const float*)d_in[0];
    const float* emb   = (const float*)d_in[1];
    const float* enc_w = (const float*)d_in[2];
    const float* enc_b = (const float*)d_in[3];
    const float* ln_w  = (const float*)d_in[4];
    const float* ln_b  = (const float*)d_in[5];
    const float* dec_w = (const float*)d_in[6];
    const float* dec_b = (const float*)d_in[7];
    float* out = (float*)d_out;

    char* ws = (char*)d_ws;
    unsigned short* qbf  = (unsigned short*)(ws);                        // 2 MB
    unsigned short* ebf  = (unsigned short*)(ws + 2097152);              // 16 MB
    float*          g    = (float*)(ws + 2097152 + 16777216);            // 512 KB
    float2*         part = (float2*)(ws + 2097152 + 16777216 + 524288);  // 4 MB

    hipLaunchKernelGGL(eprep, dim3(8192), dim3(256), 0, stream, emb, dec_w, ebf, g);
    hipLaunchKernelGGL(qprep, dim3(128),  dim3(256), 0, stream, x, enc_w, enc_b, ln_w, ln_b, qbf);
    hipLaunchKernelGGL(attn,  dim3(4096), dim3(256), 0, stream, qbf, ebf, g, part);
    hipLaunchKernelGGL(fin,   dim3(64),   dim3(256), 0, stream, part, dec_b, out);
}

// Round 9
// 152.889 us; speedup vs baseline: 1.1222x; 1.0195x over previous
//
#include <hip/hip_runtime.h>
#include <hip/hip_bf16.h>
#include <math.h>

#define NH 8
#define HS 64
#define VOCAB 16384
#define QPH 2048                         // queries per head = b(4) * t(512)
#define NSLICE 32                        // vocab slices (512 rows each)
// fold 1/sqrt(512) * log2(e) into Q so the epilogue is p = exp2(score)
#define QSCALE (0.04419417382415922f * 1.4426950408889634f)

typedef __attribute__((ext_vector_type(8))) short bf16x8;
typedef __attribute__((ext_vector_type(4))) float f32x4;

static __device__ __forceinline__ unsigned short f2bf(float f) {
    __hip_bfloat16 h = __float2bfloat16(f);
    unsigned short u;
    __builtin_memcpy(&u, &h, 2);
    return u;
}

static __device__ __forceinline__ float fexp2(float x) {
#if __has_builtin(__builtin_amdgcn_exp2f)
    return __builtin_amdgcn_exp2f(x);     // v_exp_f32 directly
#else
    return __expf(x * 0.6931471805599453f);
#endif
}

// async global->LDS. HW semantics (hard-won over R12/R16/R17):
//  - LDS dest operand = WAVE-UNIFORM base; HW adds lane*16 (divergent dest -> fault).
//  - global SRC operand = PER-LANE address (must include lane*16).
//  - one call moves exactly 1KB per wave.
static __device__ __forceinline__ void stage16(const void* g, void* l) {
    __builtin_amdgcn_global_load_lds(
        (const __attribute__((address_space(1))) void*)g,
        (__attribute__((address_space(3))) void*)l, 16, 0, 0);
}

// ---------------- Kernel 1a: eprep — coalesced read + LDS permute + g ---------------
// LINEAR coalesced f32x4 read, permute via LDS, LINEAR coalesced ushort4 write.
// ebf frag layout (R13-verified): within tile (n,T) [2048B]: byte kf*1024 + lane*16
// is lane(quad,r)'s A-frag half; chunk h*128+q*32+r*2+jh holds E[v=T*16+r][c4=h*8+q*2+jh].
// g[n][v] = E[n][v,:].dec_w via 16-lane shfl row groups.
__global__ void eprep(const float* __restrict__ emb, const float* __restrict__ dec_w,
                      unsigned short* __restrict__ ebf, float* __restrict__ g) {
    __shared__ ushort4 lu[256];
    __shared__ float red[16];
    int tid = threadIdx.x;
    int nt  = blockIdx.x;                 // n*1024 + T  (grid 8192)
    int n   = nt >> 10;
    int r   = tid >> 4;                   // row within 16-row tile
    int c4  = tid & 15;                   // f32x4 column
    f32x4 vv = ((const f32x4*)emb)[(size_t)nt * 256 + tid];   // LINEAR read
    ushort4 u = make_ushort4(f2bf(vv.x), f2bf(vv.y), f2bf(vv.z), f2bf(vv.w));
    int h = c4 >> 3, q = (c4 >> 1) & 3, jh = c4 & 1;
    lu[h * 128 + q * 32 + r * 2 + jh] = u;                    // permute via LDS
    const float* dw = dec_w + n * 64 + c4 * 4;
    float p = vv.x * dw[0] + vv.y * dw[1] + vv.z * dw[2] + vv.w * dw[3];
    p += __shfl_xor(p, 1); p += __shfl_xor(p, 2);
    p += __shfl_xor(p, 4); p += __shfl_xor(p, 8);             // 16-lane row group
    if (c4 == 0) red[r] = p;
    __syncthreads();
    ((ushort4*)ebf)[(size_t)nt * 256 + tid] = lu[tid];        // LINEAR write
    if (tid < 16) g[n * VOCAB + (nt & 1023) * 16 + tid] = red[tid];
}

// ---------------- Kernel 1b: qprep — one wave per t (grid 512 x 64) ------------------
// R19: grid 128x256 -> 512x64 (same work, 4x more blocks — was 0.5 blocks/CU).
// Frag-ordered 64-q granules (R15-verified):
//   short idx = (n*32 + q>>6)*4096 + ((qt*2+kf)*4 + quad)*128 + l15*8 + j
__global__ void qprep(const float* __restrict__ x, const float* __restrict__ enc_w,
                      const float* __restrict__ enc_b, const float* __restrict__ ln_w,
                      const float* __restrict__ ln_b, unsigned short* __restrict__ qbf) {
    int h = threadIdx.x;                  // block = one wave (64)
    int t = blockIdx.x;                   // grid 512
    float h2  = (float)(h & ~1);
    float div = __expf(h2 * (-9.210340371976184f / 64.0f));
    float ang = (float)t * div;
    float pe  = (h & 1) ? __cosf(ang) : __sinf(ang);
    float lw = ln_w[h], lb = ln_b[h];
    int kf = h >> 5, quad = (h >> 3) & 3, j = h & 7;
    int fragoff = ((kf * 4 + quad) * 128) + j;   // + qt*1024 + l15*8 added per row
    #pragma unroll
    for (int n = 0; n < NH; ++n) {
        float ew = enc_w[n * 64 + h];
        float eb = enc_b[n * 64 + h];
        #pragma unroll
        for (int b = 0; b < 4; ++b) {
            int q = b * 512 + t;
            float v = x[q] * ew + eb + pe;
            float s = v;
            #pragma unroll
            for (int off = 1; off < 64; off <<= 1) s += __shfl_xor(s, off);
            float mu = s * (1.0f / 64.0f);
            float dd = v - mu;
            float s2 = dd * dd;
            #pragma unroll
            for (int off = 1; off < 64; off <<= 1) s2 += __shfl_xor(s2, off);
            float var = s2 * (1.0f / 64.0f);
            float y = dd * rsqrtf(var + 1e-5f) * lw + lb;
            int qt = (q >> 4) & 3, l15 = q & 15;
            size_t idx = ((size_t)(n * 32 + (q >> 6)) * 4096)
                       + qt * 1024 + l15 * 8 + fragoff;
            qbf[idx] = f2bf(y * QSCALE);
        }
    }
}

// ---------------- Kernel 2: attn (R19 — R18 + parity-unrolled imm-offset body) ------
// Memory structure IDENTICAL to R18 (passed, no spill, conflicts 0): grid 4096,
// 128q x 512v blocks, E 8KB tiles DMA'd into LDS dbuf 1 ahead, Q/g in LDS,
// barrier per tile. R18's failure mode was VALU OVERHEAD: 665 cy/wave-iter measured
// vs 384 essential — runtime address math for 13 ds_reads + staging chains.
// R19: it-loop unrolled x2 with PARITY as a compile-time constant:
//  - all ds_reads become base + IMMEDIATE offset (Q: 1 base reg, offsets 0..3072;
//    E: lane*16 base, offsets P*8192+vt*2048+{0,1024}; gv: 1 base, +128 fl/outer).
//  - staging src = one running pointer += 8192/body; dest parity compile-time.
//  - tile-wrap stage replaced by uniform guard (BODY(1) stages only when o<3).
// Q re-reads stay transient (the per-body __syncthreads is a full fence — no LICM,
// no spill; proven by R18's VGPR=52/WRITE=4096).
// TRIPWIRE: WRITE_SIZE must stay 4096KB exactly; VGPR <= 64.
__global__ void __launch_bounds__(256, 4)
attn(const unsigned short* __restrict__ qbf, const unsigned short* __restrict__ ebf,
     const float* __restrict__ g, float2* __restrict__ part) {
    __shared__ __attribute__((aligned(16))) char smem[16384 + 16384 + 2048];
    char*  elds = smem;                      // [2][8192] E double-buffer
    char*  qlds = smem + 16384;              // 16KB: 128q frag-ordered (2 granules)
    float* glds = (float*)(smem + 32768);    // 512 floats

    int tid  = threadIdx.x;
    int w    = tid >> 6;
    int lane = tid & 63;
    int quad = lane >> 4;
    int l15  = lane & 15;
    int head   = blockIdx.x & 7;
    int vslice = (blockIdx.x >> 3) & 31;   // 32 slices x 512 v
    int qgroup = blockIdx.x >> 8;          // 16 groups x 128 q

    const char* qsrc = (const char*)qbf + (size_t)(head * 32 + qgroup * 2) * 8192;
    const char* esrc = (const char*)ebf + (size_t)head * 2097152 + (size_t)vslice * 65536;
    const char* gsrc = (const char*)(g + head * VOCAB + vslice * 512);

    // prologue: stage Q (16KB), g (2KB), E tile 0 (8KB) — identical to R18 (verified).
    #pragma unroll
    for (int k = 0; k < 4; ++k)
        stage16(qsrc + k * 4096 + w * 1024 + lane * 16, qlds + k * 4096 + w * 1024);
    if (w < 2)
        stage16(gsrc + w * 1024 + lane * 16, (char*)glds + w * 1024);
    stage16(esrc + w * 2048 +        lane * 16, elds + w * 2048);
    stage16(esrc + w * 2048 + 1024 + lane * 16, elds + w * 2048 + 1024);
    __syncthreads();   // vmcnt(0) drain + barrier

    float num0 = 0.f, num1 = 0.f, den0 = 0.f, den1 = 0.f;
    const f32x4 z = {0.f, 0.f, 0.f, 0.f};

    // per-lane base registers (computed once; in-loop = immediates only)
    const char*  qb   = qlds + (w >> 1) * 8192 + ((2 * w) & 3) * 2048 + lane * 16;
    const char*  el   = elds + lane * 16;          // + P*8192 + vt*2048 + {0,1024} imm
    const float* glq  = glds + quad * 4;           // + P*64 + vt*16 imm; +=128/outer
    const char*  ssrc = esrc + 8192 + w * 2048 + lane * 16;  // tile-1 src, +=8192/body
    char* sd0 = elds +        w * 2048;            // stage dest, buffer 0
    char* sd1 = elds + 8192 + w * 2048;            // stage dest, buffer 1

#define AT_BODY(P, DO_STAGE)                                                   \
    {                                                                          \
        if (DO_STAGE) {                                                        \
            char* nd_ = (P) ? sd0 : sd1;   /* tile it+1 -> buffer (1-P) */     \
            stage16(ssrc,        nd_);                                         \
            stage16(ssrc + 1024, nd_ + 1024);                                  \
            ssrc += 8192;                                                      \
        }                                                                      \
        bf16x8 q00 = *(const bf16x8*)(qb);                                     \
        bf16x8 q01 = *(const bf16x8*)(qb + 1024);                              \
        bf16x8 q10 = *(const bf16x8*)(qb + 2048);                              \
        bf16x8 q11 = *(const bf16x8*)(qb + 3072);                              \
        _Pragma("unroll")                                                      \
        for (int vt = 0; vt < 4; ++vt) {                                       \
            bf16x8 a0 = *(const bf16x8*)(el + (P) * 8192 + vt * 2048);         \
            bf16x8 a1 = *(const bf16x8*)(el + (P) * 8192 + vt * 2048 + 1024);  \
            f32x4 gv  = *(const f32x4*)(glq + (P) * 64 + vt * 16);             \
            f32x4 acc0 = __builtin_amdgcn_mfma_f32_16x16x32_bf16(a0, q00, z, 0, 0, 0); \
            acc0       = __builtin_amdgcn_mfma_f32_16x16x32_bf16(a1, q01, acc0, 0, 0, 0); \
            f32x4 acc1 = __builtin_amdgcn_mfma_f32_16x16x32_bf16(a0, q10, z, 0, 0, 0); \
            acc1       = __builtin_amdgcn_mfma_f32_16x16x32_bf16(a1, q11, acc1, 0, 0, 0); \
            _Pragma("unroll")                                                  \
            for (int r = 0; r < 4; ++r) {                                      \
                float p0 = fexp2(acc0[r]);                                     \
                float p1 = fexp2(acc1[r]);                                     \
                den0 += p0; num0 += p0 * gv[r];                                \
                den1 += p1; num1 += p1 * gv[r];                                \
            }                                                                  \
        }                                                                      \
        __syncthreads();   /* readers done with buf P; DMA into buf 1-P drained */ \
    }

    #pragma clang loop unroll(disable)
    for (int o = 0; o < 4; ++o) {
        AT_BODY(0, true);        // it = 2o   (reads buf0, stages tile 2o+1 -> buf1)
        AT_BODY(1, (o < 3));     // it = 2o+1 (reads buf1, stages tile 2o+2 -> buf0)
        glq += 128;              // advance g window by 128 floats (2 tiles)
    }
#undef AT_BODY

    // reduce across quads (same l15 = same q)
    num0 += __shfl_xor(num0, 16); num0 += __shfl_xor(num0, 32);
    den0 += __shfl_xor(den0, 16); den0 += __shfl_xor(den0, 32);
    num1 += __shfl_xor(num1, 16); num1 += __shfl_xor(num1, 32);
    den1 += __shfl_xor(den1, 16); den1 += __shfl_xor(den1, 32);
    // slotted partials: quad 0 commits qt=2w, quad 1 commits qt=2w+1
    if (quad < 2) {
        float nv = quad ? num1 : num0;     // cndmask, no runtime array index
        float dv = quad ? den1 : den0;
        int qg = qgroup * 128 + (w * 2 + quad) * 16 + l15;
        part[((size_t)vslice * NH + head) * QPH + qg] = make_float2(nv, dv);
    }
}

// ---------------- Kernel 3: fin — parallel over (n,q), LDS reduce over n -------------
__global__ void fin(const float2* __restrict__ part, const float* __restrict__ dec_b,
                    float* __restrict__ out) {
    __shared__ float red[8][32];
    int t  = threadIdx.x;
    int ql = t & 31;
    int n  = t >> 5;
    int q  = blockIdx.x * 32 + ql;
    float nv = 0.f, dv = 0.f;
    #pragma unroll            // full unroll: 32 outstanding 8B loads
    for (int sl = 0; sl < NSLICE; ++sl) {
        float2 nd = part[((size_t)sl * NH + n) * QPH + q];
        nv += nd.x; dv += nd.y;
    }
    red[n][ql] = nv / dv;
    __syncthreads();
    if (t < 32) {
        float s = dec_b[0];
        #pragma unroll
        for (int m = 0; m < NH; ++m) s += red[m][t];
        out[q] = s;
    }
}

extern "C" void kernel_launch(void* const* d_in, const int* in_sizes, int n_in,
                              void* d_out, int out_size, void* d_ws, size_t ws_size,
                              hipStream_t stream) {
    const float* x     = (const float*)d_in[0];
    const float* emb   = (const float*)d_in[1];
    const float* enc_w = (const float*)d_in[2];
    const float* enc_b = (const float*)d_in[3];
    const float* ln_w  = (const float*)d_in[4];
    const float* ln_b  = (const float*)d_in[5];
    const float* dec_w = (const float*)d_in[6];
    const float* dec_b = (const float*)d_in[7];
    float* out = (float*)d_out;

    char* ws = (char*)d_ws;
    unsigned short* qbf  = (unsigned short*)(ws);                        // 2 MB
    unsigned short* ebf  = (unsigned short*)(ws + 2097152);              // 16 MB
    float*          g    = (float*)(ws + 2097152 + 16777216);            // 512 KB
    float2*         part = (float2*)(ws + 2097152 + 16777216 + 524288);  // 4 MB

    hipLaunchKernelGGL(eprep, dim3(8192), dim3(256), 0, stream, emb, dec_w, ebf, g);
    hipLaunchKernelGGL(qprep, dim3(512),  dim3(64),  0, stream, x, enc_w, enc_b, ln_w, ln_b, qbf);
    hipLaunchKernelGGL(attn,  dim3(4096), dim3(256), 0, stream, qbf, ebf, g, part);
    hipLaunchKernelGGL(fin,   dim3(64),   dim3(256), 0, stream, part, dec_b, out);
}